// Round 1
// baseline (309.615 us; speedup 1.0000x reference)
//
#include <hip/hip_runtime.h>
#include <climits>

// ---------------------------------------------------------------------------
// RelativeMultiHeadAttentionBlock (Transformer-XL style) on MI355X (gfx950)
// B=2, T=C=1024, M=1024, S=2048, H=16, HD=64, F=1024. fp32 in/out, bf16 MFMA.
//
// Key facts exploited:
//  - mem_state's k/v are sliced away by the reference -> skip entirely.
//    k_att = [cache_key, x@Wk], val_att = [cache_value, x@Wv];
//    new_key = x@Wk, new_value = x@Wv.
//  - rel-shift+mask == bias[i][j] = scale*(q+v)[i] . r[j-i+1023], j<=i+1024.
//  - flash attention (never materialize 256 MB logits); rel bias computed
//    in-tile via MFMA vs a 32-row r band + diagonal shfl-gather; r staged in
//    a 256-row LDS ring that slides with the key loop.
// ---------------------------------------------------------------------------

typedef unsigned short u16;
typedef short bf16x8 __attribute__((ext_vector_type(8)));
typedef float f32x4 __attribute__((ext_vector_type(4)));

__device__ __forceinline__ f32x4 mfma16x16x32(bf16x8 a, bf16x8 b, f32x4 c) {
  return __builtin_amdgcn_mfma_f32_16x16x32_bf16(a, b, c, 0, 0, 0);
}

__device__ __forceinline__ u16 f2bf(float f) {  // RNE f32->bf16
  unsigned u = __builtin_bit_cast(unsigned, f);
  u = (u + 0x7FFFu + ((u >> 16) & 1u)) >> 16;
  return (u16)u;
}

__device__ __forceinline__ void gll16(const void* g, void* l) {
  __builtin_amdgcn_global_load_lds(
      (const __attribute__((address_space(1))) void*)g,
      (__attribute__((address_space(3))) void*)l, 16, 0, 0);
}

// --- segment ids ------------------------------------------------------------
__global__ __launch_bounds__(64) void seg_scan_kernel(
    const int* __restrict__ mask, const int* __restrict__ mem_mask,
    const int* __restrict__ cache_mask, int* __restrict__ qseg,
    int* __restrict__ kseg) {
  __shared__ int cs[3072];
  int b = blockIdx.x, lane = threadIdx.x;
  int carry = 0;
  for (int base = 0; base < 3072; base += 64) {
    int idx = base + lane;
    int val;
    if (idx < 1024)      val = mem_mask[b * 1024 + idx];
    else if (idx < 2048) val = cache_mask[b * 1024 + idx - 1024];
    else                 val = mask[b * 1024 + idx - 2048];
    for (int o = 1; o < 64; o <<= 1) {
      int n = __shfl_up(val, o);
      if (lane >= o) val += n;
    }
    val += carry;
    cs[idx] = val;
    carry = __shfl(val, 63);
  }
  __syncthreads();
  int mx = INT_MIN;
  for (int i = lane; i < 2048; i += 64) mx = max(mx, cs[i]);
  for (int o = 1; o < 64; o <<= 1) mx = max(mx, __shfl_xor(mx, o));
  int cs2047 = cs[2047];
  for (int t = lane; t < 1024; t += 64) qseg[b * 1024 + t] = cs[2048 + t] - cs2047 + mx;
  for (int j = lane; j < 2048; j += 64) kseg[b * 2048 + j] = cs[1024 + j];
}

// --- preps ------------------------------------------------------------------
__global__ __launch_bounds__(256) void cvt_bf16_kernel(const float* __restrict__ src,
                                                       u16* __restrict__ dst, int n) {
  int i = (blockIdx.x * 256 + threadIdx.x) * 4;
  if (i >= n) return;
  float4 v = *(const float4*)(src + i);
  dst[i + 0] = f2bf(v.x); dst[i + 1] = f2bf(v.y);
  dst[i + 2] = f2bf(v.z); dst[i + 3] = f2bf(v.w);
}

__global__ __launch_bounds__(256) void tr_w_kernel(const float* __restrict__ src,
                                                   u16* __restrict__ dst) {
  __shared__ float tile[32][33];
  int tx = threadIdx.x & 31, ty = threadIdx.x >> 5;
  int r0 = blockIdx.y * 32, c0 = blockIdx.x * 32;
#pragma unroll
  for (int i = 0; i < 32; i += 8)
    tile[ty + i][tx] = src[(size_t)(r0 + ty + i) * 1024 + c0 + tx];
  __syncthreads();
#pragma unroll
  for (int i = 0; i < 32; i += 8)
    dst[(size_t)(c0 + ty + i) * 1024 + r0 + tx] = f2bf(tile[tx][ty + i]);
}

__global__ __launch_bounds__(256) void ck_perm_kernel(const float* __restrict__ src,
                                                      u16* __restrict__ dst) {
  int i = blockIdx.x * 256 + threadIdx.x;  // 524288 quads
  int dq = i & 15, h = (i >> 4) & 15, t = (i >> 8) & 1023, b = i >> 18;
  float4 v = *(const float4*)(src + (size_t)i * 4);
  size_t o = (((size_t)(b * 16 + h)) * 2048 + t) * 64 + dq * 4;
  dst[o + 0] = f2bf(v.x); dst[o + 1] = f2bf(v.y);
  dst[o + 2] = f2bf(v.z); dst[o + 3] = f2bf(v.w);
}

__global__ __launch_bounds__(256) void cv_tr_kernel(const float* __restrict__ src,
                                                    u16* __restrict__ dst) {
  __shared__ float tile[32][33];
  int bh = blockIdx.z, b = bh >> 4, h = bh & 15;
  int t0 = blockIdx.x * 32, d0 = blockIdx.y * 32;
  int tx = threadIdx.x & 31, ty = threadIdx.x >> 5;
#pragma unroll
  for (int i = 0; i < 32; i += 8)
    tile[ty + i][tx] = src[(((size_t)b * 1024 + t0 + ty + i) * 16 + h) * 64 + d0 + tx];
  __syncthreads();
#pragma unroll
  for (int i = 0; i < 32; i += 8)
    dst[((size_t)bh * 64 + d0 + ty + i) * 2048 + t0 + tx] = f2bf(tile[tx][ty + i]);
}

// --- projection / output GEMM ----------------------------------------------
// C[m][n] = sum_k A[m][k]*W[n][k]; 64x64 tile, 4 waves, BK=64, swizzled LDS,
// global_load_lds(16B) staging with pre-swizzled source (m173).
// mode: 0=q(->qu,qv with +u/+v) 1=k(new_key,kbuf) 2=v(new_value,vtbuf) 3=r 4=out
__global__ __launch_bounds__(256) void gemm_proj_kernel(
    const u16* __restrict__ xbf, const u16* __restrict__ relbf,
    const u16* __restrict__ obf, const u16* __restrict__ wt5,
    u16* __restrict__ qu, u16* __restrict__ qv, u16* __restrict__ kbuf,
    u16* __restrict__ vtbuf, u16* __restrict__ rbuf, float* __restrict__ dout,
    const float* __restrict__ uvec, const float* __restrict__ vvec, int movr) {
  __shared__ __align__(16) u16 lA[64 * 64];
  __shared__ __align__(16) u16 lB[64 * 64];
  const int mode = (movr >= 0) ? movr : (int)blockIdx.z;
  const u16* A = (mode == 3) ? relbf : ((mode == 4) ? obf : xbf);
  const u16* Wm = wt5 + (size_t)mode * 1048576;
  const int tid = threadIdx.x;
  const int lane = tid & 63, gq = lane >> 4, cl = lane & 15;
  const int wv = tid >> 6, wm = wv >> 1, wn = wv & 1;
  const int by = blockIdx.y * 64, bx = blockIdx.x * 64;
  const f32x4 fz = {0.f, 0.f, 0.f, 0.f};

  f32x4 acc[2][2];
#pragma unroll
  for (int a = 0; a < 2; ++a)
#pragma unroll
    for (int bq = 0; bq < 2; ++bq) acc[a][bq] = fz;

  const int off0 = tid * 16, off1 = tid * 16 + 4096;
  const int L0 = off0 ^ (((off0 >> 7) & 7) << 4);
  const int L1 = off1 ^ (((off1 >> 7) & 7) << 4);
  const int rr0 = off0 >> 7, ke0 = (L0 & 127) >> 1;
  const int rr1 = off1 >> 7, ke1 = (L1 & 127) >> 1;
  const u16* pA0 = A + (size_t)(by + rr0) * 1024 + ke0;
  const u16* pA1 = A + (size_t)(by + rr1) * 1024 + ke1;
  const u16* pB0 = Wm + (size_t)(bx + rr0) * 1024 + ke0;
  const u16* pB1 = Wm + (size_t)(bx + rr1) * 1024 + ke1;

  for (int k0 = 0; k0 < 1024; k0 += 64) {
    gll16(pA0 + k0, (char*)lA + off0);
    gll16(pA1 + k0, (char*)lA + off1);
    gll16(pB0 + k0, (char*)lB + off0);
    gll16(pB1 + k0, (char*)lB + off1);
    __syncthreads();
    bf16x8 af[2][2], bff[2][2];
#pragma unroll
    for (int mi = 0; mi < 2; ++mi)
#pragma unroll
      for (int kb = 0; kb < 2; ++kb) {
        int row = wm * 32 + mi * 16 + cl;
        int byte = row * 128 + kb * 64 + gq * 16;
        byte ^= ((row & 7) << 4);
        af[mi][kb] = *(const bf16x8*)((const char*)lA + byte);
      }
#pragma unroll
    for (int ni = 0; ni < 2; ++ni)
#pragma unroll
      for (int kb = 0; kb < 2; ++kb) {
        int row = wn * 32 + ni * 16 + cl;
        int byte = row * 128 + kb * 64 + gq * 16;
        byte ^= ((row & 7) << 4);
        bff[ni][kb] = *(const bf16x8*)((const char*)lB + byte);
      }
#pragma unroll
    for (int mi = 0; mi < 2; ++mi)
#pragma unroll
      for (int ni = 0; ni < 2; ++ni) {
        acc[mi][ni] = mfma16x16x32(af[mi][0], bff[ni][0], acc[mi][ni]);
        acc[mi][ni] = mfma16x16x32(af[mi][1], bff[ni][1], acc[mi][ni]);
      }
    __syncthreads();
  }

#pragma unroll
  for (int mi = 0; mi < 2; ++mi)
#pragma unroll
    for (int ni = 0; ni < 2; ++ni) {
      int n = bx + wn * 32 + ni * 16 + cl;
      float ub = 0.f, vb = 0.f;
      if (mode == 0) { ub = uvec[n]; vb = vvec[n]; }
#pragma unroll
      for (int r = 0; r < 4; ++r) {
        int m = by + wm * 32 + mi * 16 + 4 * gq + r;
        float val = acc[mi][ni][r];
        if (mode == 0) {
          qu[(size_t)m * 1024 + n] = f2bf(val + ub);
          qv[(size_t)m * 1024 + n] = f2bf(val + vb);
        } else if (mode == 1) {
          dout[2097152 + (size_t)m * 1024 + n] = val;
          kbuf[(((size_t)((m >> 10) * 16 + (n >> 6))) * 2048 + 1024 + (m & 1023)) * 64 +
               (n & 63)] = f2bf(val);
        } else if (mode == 2) {
          dout[4194304 + (size_t)m * 1024 + n] = val;
          vtbuf[(((size_t)((m >> 10) * 16 + (n >> 6))) * 64 + (n & 63)) * 2048 + 1024 +
                (m & 1023)] = f2bf(val);
        } else if (mode == 3) {
          rbuf[((size_t)(n >> 6) * 2048 + m) * 64 + (n & 63)] = f2bf(val);
        } else {
          dout[(size_t)m * 1024 + n] = val;
        }
      }
    }
}

// --- flash attention with in-tile relative bias -----------------------------
__global__ __launch_bounds__(256) void attn_kernel(
    const u16* __restrict__ qu, const u16* __restrict__ qv,
    const u16* __restrict__ kbuf, const u16* __restrict__ vtbuf,
    const u16* __restrict__ rbuf, const int* __restrict__ qseg,
    const int* __restrict__ kseg, u16* __restrict__ obf) {
  __shared__ __align__(16) u16 ldsK[32 * 64];
  __shared__ __align__(16) u16 ldsV[64 * 64];
  __shared__ __align__(16) u16 ldsR[256 * 64];
  __shared__ __align__(16) u16 ldsP[8 * 1024];

  const int tid = threadIdx.x, lane = tid & 63;
  const int gq = lane >> 4, cl = lane & 15;
  const int wv = tid >> 6;
  const int bi = blockIdx.x * 128, h = blockIdx.y, b = blockIdx.z;
  const int bh = b * 16 + h;
  const int iA = bi + wv * 32, iB = iA + 16;
  const f32x4 fz = {0.f, 0.f, 0.f, 0.f};

  bf16x8 aU[2][2], aV[2][2];
#pragma unroll
  for (int mi = 0; mi < 2; ++mi) {
    int irow = (mi ? iB : iA) + cl;
#pragma unroll
    for (int kb = 0; kb < 2; ++kb) {
      size_t off = ((size_t)b * 1024 + irow) * 1024 + h * 64 + kb * 32 + gq * 8;
      aU[mi][kb] = *(const bf16x8*)(qu + off);
      aV[mi][kb] = *(const bf16x8*)(qv + off);
    }
  }
  int qsv[2][4];
#pragma unroll
  for (int mi = 0; mi < 2; ++mi)
#pragma unroll
    for (int r = 0; r < 4; ++r)
      qsv[mi][r] = qseg[b * 1024 + (mi ? iB : iA) + 4 * gq + r];

  float mrun[2][4], lrun[2][4];
  f32x4 oacc[2][4];
#pragma unroll
  for (int mi = 0; mi < 2; ++mi) {
#pragma unroll
    for (int r = 0; r < 4; ++r) { mrun[mi][r] = -1e30f; lrun[mi][r] = 0.f; }
#pragma unroll
    for (int di = 0; di < 4; ++di) oacc[mi][di] = fz;
  }

#pragma unroll
  for (int p = 0; p < 4; ++p) {  // pre-stage r rows [896-bi, 1023-bi]
    int e0 = 896 - bi + 32 * p;
    int sb = e0 & 255;
    int off = sb * 128 + tid * 16;
    int L = off ^ (((off >> 7) & 7) << 4);
    int slot = off >> 7;
    int rlog = e0 + (slot - sb);
    int d = (L & 127) >> 1;
    gll16(rbuf + ((size_t)h * 2048 + rlog) * 64 + d, (char*)ldsR + off);
  }

  const int jend = bi + 1120;
  for (int j0 = 0; j0 <= jend; j0 += 32) {
    {
      int off = tid * 16;
      int L = off ^ (((off >> 7) & 7) << 4);
      int s = off >> 7;
      int d = (L & 127) >> 1;
      gll16(kbuf + ((size_t)bh * 2048 + (j0 + s)) * 64 + d, (char*)ldsK + off);
    }
#pragma unroll
    for (int c2 = 0; c2 < 2; ++c2) {
      int off = c2 * 4096 + tid * 16;
      int L = off ^ (((off >> 7) & 7) << 4);
      int d = off >> 7;
      int se = ((L & 127) >> 1) & 31;
      gll16(vtbuf + ((size_t)bh * 64 + d) * 2048 + j0 + se, (char*)ldsV + off);
    }
    {
      int e0 = j0 - bi + 1024;
      int sb = e0 & 255;
      int off = sb * 128 + tid * 16;
      int L = off ^ (((off >> 7) & 7) << 4);
      int slot = off >> 7;
      int rlog = e0 + (slot - sb);
      int d = (L & 127) >> 1;
      int rc = rlog > 2047 ? 2047 : rlog;
      gll16(rbuf + ((size_t)h * 2048 + rc) * 64 + d, (char*)ldsR + off);
    }
    __syncthreads();

    bf16x8 vfr[4];
#pragma unroll
    for (int di = 0; di < 4; ++di) {
      int row = di * 16 + cl;
      int byte = row * 128 + gq * 16;
      byte ^= ((row & 7) << 4);
      vfr[di] = *(const bf16x8*)((const char*)ldsV + byte);
    }
    bf16x8 kf[2][2];
#pragma unroll
    for (int jt = 0; jt < 2; ++jt)
#pragma unroll
      for (int kb = 0; kb < 2; ++kb) {
        int row = jt * 16 + cl;
        int byte = row * 128 + kb * 64 + gq * 16;
        byte ^= ((row & 7) << 4);
        kf[jt][kb] = *(const bf16x8*)((const char*)ldsK + byte);
      }
    int ksv0 = kseg[(size_t)b * 2048 + j0 + cl];
    int ksv1 = kseg[(size_t)b * 2048 + j0 + 16 + cl];

#pragma unroll
    for (int mi = 0; mi < 2; ++mi) {
      const int im = mi ? iB : iA;
      char* Pm = (char*)ldsP + (size_t)(wv * 2 + mi) * 2048;
      f32x4 xq[2], bd0[2], bd1[2];
#pragma unroll
      for (int jt = 0; jt < 2; ++jt) {
        f32x4 a = fz;
        a = mfma16x16x32(aU[mi][0], kf[jt][0], a);
        a = mfma16x16x32(aU[mi][1], kf[jt][1], a);
        xq[jt] = a;
#pragma unroll
        for (int rt = 0; rt < 2; ++rt) {
          int Rb = j0 + jt * 16 - im + 1008 + rt * 16;
          int slot = (Rb + cl) & 255;
          int sw = ((slot & 7) << 4);
          bf16x8 rf0 = *(const bf16x8*)((const char*)ldsR + ((slot * 128 + gq * 16) ^ sw));
          bf16x8 rf1 = *(const bf16x8*)((const char*)ldsR + ((slot * 128 + 64 + gq * 16) ^ sw));
          f32x4 t = fz;
          t = mfma16x16x32(aV[mi][0], rf0, t);
          t = mfma16x16x32(aV[mi][1], rf1, t);
          if (rt == 0) bd0[jt] = t; else bd1[jt] = t;
        }
      }
      float x0[4], x1[4], alf[4];
#pragma unroll
      for (int r = 0; r < 4; ++r) {
        int ri = 4 * gq + r;
        int lc = cl - ri + 15;
        int srcl = (gq << 4) | (lc & 15);
        float a00 = __shfl(bd0[0][r], srcl);
        float a01 = __shfl(bd1[0][r], srcl);
        float bdv0 = (lc < 16) ? a00 : a01;
        float a10 = __shfl(bd0[1][r], srcl);
        float a11 = __shfl(bd1[1][r], srcl);
        float bdv1 = (lc < 16) ? a10 : a11;
        int i_abs = im + ri;
        bool v0 = ((j0 + cl) <= i_abs + 1024) && (ksv0 == qsv[mi][r]);
        bool v1 = ((j0 + 16 + cl) <= i_abs + 1024) && (ksv1 == qsv[mi][r]);
        x0[r] = v0 ? (xq[0][r] + bdv0) * 0.125f : -1e30f;
        x1[r] = v1 ? (xq[1][r] + bdv1) * 0.125f : -1e30f;
      }
#pragma unroll
      for (int r = 0; r < 4; ++r) {
        float mx = fmaxf(x0[r], x1[r]);
        mx = fmaxf(mx, __shfl_xor(mx, 1));
        mx = fmaxf(mx, __shfl_xor(mx, 2));
        mx = fmaxf(mx, __shfl_xor(mx, 4));
        mx = fmaxf(mx, __shfl_xor(mx, 8));
        float mold = mrun[mi][r];
        float mnew = fmaxf(mold, mx);
        float al = __expf(mold - mnew);
        float p0 = __expf(x0[r] - mnew);
        float p1 = __expf(x1[r] - mnew);
        float s = p0 + p1;
        s += __shfl_xor(s, 1); s += __shfl_xor(s, 2);
        s += __shfl_xor(s, 4); s += __shfl_xor(s, 8);
        mrun[mi][r] = mnew;
        lrun[mi][r] = lrun[mi][r] * al + s;
        alf[r] = al;
        int ri = 4 * gq + r;
        int bb = ((ri & 7) << 4);
        *(u16*)(Pm + ((ri * 128 + cl * 2) ^ bb)) = f2bf(p0);
        *(u16*)(Pm + ((ri * 128 + (16 + cl) * 2) ^ bb)) = f2bf(p1);
      }
      f32x4 av = {alf[0], alf[1], alf[2], alf[3]};
#pragma unroll
      for (int di = 0; di < 4; ++di) oacc[mi][di] *= av;
      bf16x8 pf;
      {
        int byte = cl * 128 + gq * 16;
        byte ^= ((cl & 7) << 4);
        pf = *(const bf16x8*)((const char*)Pm + byte);
      }
#pragma unroll
      for (int di = 0; di < 4; ++di)
        oacc[mi][di] = mfma16x16x32(pf, vfr[di], oacc[mi][di]);
    }
    __syncthreads();
  }

#pragma unroll
  for (int mi = 0; mi < 2; ++mi) {
    const int im = mi ? iB : iA;
    f32x4 iv = {1.0f / lrun[mi][0], 1.0f / lrun[mi][1], 1.0f / lrun[mi][2],
                1.0f / lrun[mi][3]};
#pragma unroll
    for (int di = 0; di < 4; ++di) {
      f32x4 ov = oacc[mi][di] * iv;
#pragma unroll
      for (int r = 0; r < 4; ++r) {
        size_t row = (size_t)b * 1024 + im + 4 * gq + r;
        obf[row * 1024 + h * 64 + di * 16 + cl] = f2bf(ov[r]);
      }
    }
  }
}

// ---------------------------------------------------------------------------
extern "C" void kernel_launch(void* const* d_in, const int* in_sizes, int n_in,
                              void* d_out, int out_size, void* d_ws, size_t ws_size,
                              hipStream_t stream) {
  (void)in_sizes; (void)n_in; (void)out_size; (void)ws_size;
  const float* x           = (const float*)d_in[0];
  const int*   mask        = (const int*)d_in[1];
  const int*   mem_mask    = (const int*)d_in[3];
  const float* cache_key   = (const float*)d_in[4];
  const float* cache_value = (const float*)d_in[5];
  const int*   cache_mask  = (const int*)d_in[6];
  const float* rel_emb     = (const float*)d_in[7];
  const float* Wq          = (const float*)d_in[8];
  const float* Wk          = (const float*)d_in[9];
  const float* Wv          = (const float*)d_in[10];
  const float* Wr          = (const float*)d_in[11];
  const float* uvec        = (const float*)d_in[12];
  const float* vvec        = (const float*)d_in[13];
  const float* Wo          = (const float*)d_in[14];
  float* dout = (float*)d_out;

  char* W = (char*)d_ws;  // ~50.1 MB of workspace used
  u16* xbf   = (u16*)(W + (0u << 20));
  u16* relbf = (u16*)(W + (4u << 20));
  u16* wt5   = (u16*)(W + (8u << 20));
  u16* kbuf  = (u16*)(W + (18u << 20));
  u16* vtbuf = (u16*)(W + (26u << 20));
  u16* rbuf  = (u16*)(W + (34u << 20));
  u16* qu    = (u16*)(W + (38u << 20));
  u16* qv    = (u16*)(W + (42u << 20));
  u16* obf   = (u16*)(W + (46u << 20));
  int* qseg  = (int*)(W + (50u << 20));
  int* kseg  = (int*)(W + (50u << 20) + 8192);

  seg_scan_kernel<<<dim3(2), dim3(64), 0, stream>>>(mask, mem_mask, cache_mask, qseg, kseg);
  cvt_bf16_kernel<<<dim3(2048), dim3(256), 0, stream>>>(x, xbf, 2097152);
  cvt_bf16_kernel<<<dim3(2048), dim3(256), 0, stream>>>(rel_emb, relbf, 2097152);
  tr_w_kernel<<<dim3(32, 32), dim3(256), 0, stream>>>(Wq, wt5);
  tr_w_kernel<<<dim3(32, 32), dim3(256), 0, stream>>>(Wk, wt5 + (1u << 20));
  tr_w_kernel<<<dim3(32, 32), dim3(256), 0, stream>>>(Wv, wt5 + (2u << 20));
  tr_w_kernel<<<dim3(32, 32), dim3(256), 0, stream>>>(Wr, wt5 + (3u << 20));
  tr_w_kernel<<<dim3(32, 32), dim3(256), 0, stream>>>(Wo, wt5 + (4u << 20));
  ck_perm_kernel<<<dim3(2048), dim3(256), 0, stream>>>(cache_key, kbuf);
  cv_tr_kernel<<<dim3(32, 2, 32), dim3(256), 0, stream>>>(cache_value, vtbuf);
  gemm_proj_kernel<<<dim3(16, 32, 4), dim3(256), 0, stream>>>(
      xbf, relbf, obf, wt5, qu, qv, kbuf, vtbuf, rbuf, dout, uvec, vvec, -1);
  attn_kernel<<<dim3(8, 16, 2), dim3(256), 0, stream>>>(qu, qv, kbuf, vtbuf, rbuf,
                                                        qseg, kseg, obf);
  gemm_proj_kernel<<<dim3(16, 32, 1), dim3(256), 0, stream>>>(
      xbf, relbf, obf, wt5, qu, qv, kbuf, vtbuf, rbuf, dout, uvec, vvec, 4);
}

// Round 2
// 279.941 us; speedup vs baseline: 1.1060x; 1.1060x over previous
//
#include <hip/hip_runtime.h>
#include <climits>

// ---------------------------------------------------------------------------
// RelativeMultiHeadAttentionBlock (Transformer-XL style) on MI355X (gfx950)
// B=2, T=C=1024, M=1024, S=2048, H=16, HD=64, F=1024. fp32 in/out, bf16 MFMA.
//
// R1: attn rebuilt for occupancy+pipelining:
//  - 64 q-rows/block (16/wave), keys split 2-way by 64-tile parity ->
//    1024 blocks (was 256), LDS 40KB (was 60KB) -> 4 blocks/CU target.
//  - K/V double-buffered, raw s_barrier + counted vmcnt(4) (T3/T4): prefetch
//    stays in flight across barriers (HIP __syncthreads would drain it).
//  - rel-emb fragments read directly from global (L2); XCD-aware block remap
//    co-locates 4 (b,h) per XCD.
//  - split-key partials (O in bf16, m/l in f32) + combine kernel. pO reuses
//    the xbf/relbf region (dead by attn time).
// ---------------------------------------------------------------------------

typedef unsigned short u16;
typedef short bf16x8 __attribute__((ext_vector_type(8)));
typedef float f32x4 __attribute__((ext_vector_type(4)));

__device__ __forceinline__ f32x4 mfma16x16x32(bf16x8 a, bf16x8 b, f32x4 c) {
  return __builtin_amdgcn_mfma_f32_16x16x32_bf16(a, b, c, 0, 0, 0);
}

__device__ __forceinline__ u16 f2bf(float f) {  // RNE f32->bf16
  unsigned u = __builtin_bit_cast(unsigned, f);
  u = (u + 0x7FFFu + ((u >> 16) & 1u)) >> 16;
  return (u16)u;
}

__device__ __forceinline__ float bf2f(u16 x) {
  unsigned u = ((unsigned)x) << 16;
  return __builtin_bit_cast(float, u);
}

__device__ __forceinline__ void gll16(const void* g, void* l) {
  __builtin_amdgcn_global_load_lds(
      (const __attribute__((address_space(1))) void*)g,
      (__attribute__((address_space(3))) void*)l, 16, 0, 0);
}

// --- segment ids ------------------------------------------------------------
__global__ __launch_bounds__(64) void seg_scan_kernel(
    const int* __restrict__ mask, const int* __restrict__ mem_mask,
    const int* __restrict__ cache_mask, int* __restrict__ qseg,
    int* __restrict__ kseg) {
  __shared__ int cs[3072];
  int b = blockIdx.x, lane = threadIdx.x;
  int carry = 0;
  for (int base = 0; base < 3072; base += 64) {
    int idx = base + lane;
    int val;
    if (idx < 1024)      val = mem_mask[b * 1024 + idx];
    else if (idx < 2048) val = cache_mask[b * 1024 + idx - 1024];
    else                 val = mask[b * 1024 + idx - 2048];
    for (int o = 1; o < 64; o <<= 1) {
      int n = __shfl_up(val, o);
      if (lane >= o) val += n;
    }
    val += carry;
    cs[idx] = val;
    carry = __shfl(val, 63);
  }
  __syncthreads();
  int mx = INT_MIN;
  for (int i = lane; i < 2048; i += 64) mx = max(mx, cs[i]);
  for (int o = 1; o < 64; o <<= 1) mx = max(mx, __shfl_xor(mx, o));
  int cs2047 = cs[2047];
  for (int t = lane; t < 1024; t += 64) qseg[b * 1024 + t] = cs[2048 + t] - cs2047 + mx;
  for (int j = lane; j < 2048; j += 64) kseg[b * 2048 + j] = cs[1024 + j];
}

// --- preps ------------------------------------------------------------------
__global__ __launch_bounds__(256) void cvt_bf16_kernel(const float* __restrict__ src,
                                                       u16* __restrict__ dst, int n) {
  int i = (blockIdx.x * 256 + threadIdx.x) * 4;
  if (i >= n) return;
  float4 v = *(const float4*)(src + i);
  dst[i + 0] = f2bf(v.x); dst[i + 1] = f2bf(v.y);
  dst[i + 2] = f2bf(v.z); dst[i + 3] = f2bf(v.w);
}

__global__ __launch_bounds__(256) void tr_w_kernel(const float* __restrict__ src,
                                                   u16* __restrict__ dst) {
  __shared__ float tile[32][33];
  int tx = threadIdx.x & 31, ty = threadIdx.x >> 5;
  int r0 = blockIdx.y * 32, c0 = blockIdx.x * 32;
#pragma unroll
  for (int i = 0; i < 32; i += 8)
    tile[ty + i][tx] = src[(size_t)(r0 + ty + i) * 1024 + c0 + tx];
  __syncthreads();
#pragma unroll
  for (int i = 0; i < 32; i += 8)
    dst[(size_t)(c0 + ty + i) * 1024 + r0 + tx] = f2bf(tile[tx][ty + i]);
}

__global__ __launch_bounds__(256) void ck_perm_kernel(const float* __restrict__ src,
                                                      u16* __restrict__ dst) {
  int i = blockIdx.x * 256 + threadIdx.x;  // 524288 quads
  int dq = i & 15, h = (i >> 4) & 15, t = (i >> 8) & 1023, b = i >> 18;
  float4 v = *(const float4*)(src + (size_t)i * 4);
  size_t o = (((size_t)(b * 16 + h)) * 2048 + t) * 64 + dq * 4;
  dst[o + 0] = f2bf(v.x); dst[o + 1] = f2bf(v.y);
  dst[o + 2] = f2bf(v.z); dst[o + 3] = f2bf(v.w);
}

__global__ __launch_bounds__(256) void cv_tr_kernel(const float* __restrict__ src,
                                                    u16* __restrict__ dst) {
  __shared__ float tile[32][33];
  int bh = blockIdx.z, b = bh >> 4, h = bh & 15;
  int t0 = blockIdx.x * 32, d0 = blockIdx.y * 32;
  int tx = threadIdx.x & 31, ty = threadIdx.x >> 5;
#pragma unroll
  for (int i = 0; i < 32; i += 8)
    tile[ty + i][tx] = src[(((size_t)b * 1024 + t0 + ty + i) * 16 + h) * 64 + d0 + tx];
  __syncthreads();
#pragma unroll
  for (int i = 0; i < 32; i += 8)
    dst[((size_t)bh * 64 + d0 + ty + i) * 2048 + t0 + tx] = f2bf(tile[tx][ty + i]);
}

// --- projection / output GEMM ----------------------------------------------
__global__ __launch_bounds__(256) void gemm_proj_kernel(
    const u16* __restrict__ xbf, const u16* __restrict__ relbf,
    const u16* __restrict__ obf, const u16* __restrict__ wt5,
    u16* __restrict__ qu, u16* __restrict__ qv, u16* __restrict__ kbuf,
    u16* __restrict__ vtbuf, u16* __restrict__ rbuf, float* __restrict__ dout,
    const float* __restrict__ uvec, const float* __restrict__ vvec, int movr) {
  __shared__ __align__(16) u16 lA[64 * 64];
  __shared__ __align__(16) u16 lB[64 * 64];
  const int mode = (movr >= 0) ? movr : (int)blockIdx.z;
  const u16* A = (mode == 3) ? relbf : ((mode == 4) ? obf : xbf);
  const u16* Wm = wt5 + (size_t)mode * 1048576;
  const int tid = threadIdx.x;
  const int lane = tid & 63, gq = lane >> 4, cl = lane & 15;
  const int wv = tid >> 6, wm = wv >> 1, wn = wv & 1;
  const int by = blockIdx.y * 64, bx = blockIdx.x * 64;
  const f32x4 fz = {0.f, 0.f, 0.f, 0.f};

  f32x4 acc[2][2];
#pragma unroll
  for (int a = 0; a < 2; ++a)
#pragma unroll
    for (int bq = 0; bq < 2; ++bq) acc[a][bq] = fz;

  const int off0 = tid * 16, off1 = tid * 16 + 4096;
  const int L0 = off0 ^ (((off0 >> 7) & 7) << 4);
  const int L1 = off1 ^ (((off1 >> 7) & 7) << 4);
  const int rr0 = off0 >> 7, ke0 = (L0 & 127) >> 1;
  const int rr1 = off1 >> 7, ke1 = (L1 & 127) >> 1;
  const u16* pA0 = A + (size_t)(by + rr0) * 1024 + ke0;
  const u16* pA1 = A + (size_t)(by + rr1) * 1024 + ke1;
  const u16* pB0 = Wm + (size_t)(bx + rr0) * 1024 + ke0;
  const u16* pB1 = Wm + (size_t)(bx + rr1) * 1024 + ke1;

  for (int k0 = 0; k0 < 1024; k0 += 64) {
    gll16(pA0 + k0, (char*)lA + off0);
    gll16(pA1 + k0, (char*)lA + off1);
    gll16(pB0 + k0, (char*)lB + off0);
    gll16(pB1 + k0, (char*)lB + off1);
    __syncthreads();
    bf16x8 af[2][2], bff[2][2];
#pragma unroll
    for (int mi = 0; mi < 2; ++mi)
#pragma unroll
      for (int kb = 0; kb < 2; ++kb) {
        int row = wm * 32 + mi * 16 + cl;
        int byte = row * 128 + kb * 64 + gq * 16;
        byte ^= ((row & 7) << 4);
        af[mi][kb] = *(const bf16x8*)((const char*)lA + byte);
      }
#pragma unroll
    for (int ni = 0; ni < 2; ++ni)
#pragma unroll
      for (int kb = 0; kb < 2; ++kb) {
        int row = wn * 32 + ni * 16 + cl;
        int byte = row * 128 + kb * 64 + gq * 16;
        byte ^= ((row & 7) << 4);
        bff[ni][kb] = *(const bf16x8*)((const char*)lB + byte);
      }
#pragma unroll
    for (int mi = 0; mi < 2; ++mi)
#pragma unroll
      for (int ni = 0; ni < 2; ++ni) {
        acc[mi][ni] = mfma16x16x32(af[mi][0], bff[ni][0], acc[mi][ni]);
        acc[mi][ni] = mfma16x16x32(af[mi][1], bff[ni][1], acc[mi][ni]);
      }
    __syncthreads();
  }

#pragma unroll
  for (int mi = 0; mi < 2; ++mi)
#pragma unroll
    for (int ni = 0; ni < 2; ++ni) {
      int n = bx + wn * 32 + ni * 16 + cl;
      float ub = 0.f, vb = 0.f;
      if (mode == 0) { ub = uvec[n]; vb = vvec[n]; }
#pragma unroll
      for (int r = 0; r < 4; ++r) {
        int m = by + wm * 32 + mi * 16 + 4 * gq + r;
        float val = acc[mi][ni][r];
        if (mode == 0) {
          qu[(size_t)m * 1024 + n] = f2bf(val + ub);
          qv[(size_t)m * 1024 + n] = f2bf(val + vb);
        } else if (mode == 1) {
          dout[2097152 + (size_t)m * 1024 + n] = val;
          kbuf[(((size_t)((m >> 10) * 16 + (n >> 6))) * 2048 + 1024 + (m & 1023)) * 64 +
               (n & 63)] = f2bf(val);
        } else if (mode == 2) {
          dout[4194304 + (size_t)m * 1024 + n] = val;
          vtbuf[(((size_t)((m >> 10) * 16 + (n >> 6))) * 64 + (n & 63)) * 2048 + 1024 +
                (m & 1023)] = f2bf(val);
        } else if (mode == 3) {
          rbuf[((size_t)(n >> 6) * 2048 + m) * 64 + (n & 63)] = f2bf(val);
        } else {
          dout[(size_t)m * 1024 + n] = val;
        }
      }
    }
}

// --- flash attention, split-key, 16 q-rows/wave ------------------------------
// grid: x in [0,32) = chunk*16 + qb, y = h, z = b  (remapped for XCD locality)
__global__ __launch_bounds__(256, 4) void attn_kernel(
    const u16* __restrict__ qu, const u16* __restrict__ qv,
    const u16* __restrict__ kbuf, const u16* __restrict__ vtbuf,
    const u16* __restrict__ rbuf, const int* __restrict__ qseg,
    const int* __restrict__ kseg, u16* __restrict__ pO,
    float* __restrict__ pml) {
  __shared__ __align__(16) u16 ldsK[2][64 * 64];
  __shared__ __align__(16) u16 ldsV[2][64 * 64];
  __shared__ __align__(16) u16 ldsP[4][16 * 64];

  const int tid = threadIdx.x, lane = tid & 63;
  const int gq = lane >> 4, cl = lane & 15;
  const int wv = tid >> 6;
  // XCD-locality remap (bijective over 1024 blocks): 4 (b,h) per XCD
  int lin = blockIdx.x + 32 * (blockIdx.y + 16 * blockIdx.z);
  lin = (lin & 7) * 128 + (lin >> 3);
  const int xx = lin & 31, bh = lin >> 5;
  const int chunk = xx >> 4, qb = xx & 15;
  const int b = bh >> 4, h = bh & 15;
  const int bi = qb * 64, i0 = bi + wv * 16;
  const int tmax = qb + 16;  // last 64-key tile index for this block
  const f32x4 fz = {0.f, 0.f, 0.f, 0.f};

  // staging addressing (linear LDS dest, pre-swizzled global source)
  const int offA = tid * 16, offB = tid * 16 + 4096;
  const int LA = offA ^ (((offA >> 7) & 7) << 4);
  const int LB = offB ^ (((offB >> 7) & 7) << 4);
  const u16* kA = kbuf + ((size_t)bh * 2048 + (offA >> 7)) * 64 + ((LA & 127) >> 1);
  const u16* kB = kbuf + ((size_t)bh * 2048 + (offB >> 7)) * 64 + ((LB & 127) >> 1);
  const u16* vA = vtbuf + ((size_t)bh * 64 + (offA >> 7)) * 2048 + ((LA & 127) >> 1);
  const u16* vB = vtbuf + ((size_t)bh * 64 + (offB >> 7)) * 2048 + ((LB & 127) >> 1);

#define STAGE(T, BUFI)                                            \
  do {                                                            \
    gll16(kA + (size_t)(T) * 4096, (char*)ldsK[BUFI] + offA);     \
    gll16(kB + (size_t)(T) * 4096, (char*)ldsK[BUFI] + offB);     \
    gll16(vA + (T) * 64, (char*)ldsV[BUFI] + offA);               \
    gll16(vB + (T) * 64, (char*)ldsV[BUFI] + offB);               \
  } while (0)

  STAGE(chunk, 0);  // prologue prefetch (in flight during Q setup)

  // Q fragments (A-frag: row=lane&15, k=32*kb+8*gq+j)
  bf16x8 aU[2], aV[2];
#pragma unroll
  for (int kb = 0; kb < 2; ++kb) {
    size_t off = ((size_t)b * 1024 + i0 + cl) * 1024 + h * 64 + kb * 32 + gq * 8;
    aU[kb] = *(const bf16x8*)(qu + off);
    aV[kb] = *(const bf16x8*)(qv + off);
  }
  int qsv[4];
#pragma unroll
  for (int r = 0; r < 4; ++r) qsv[r] = qseg[b * 1024 + i0 + 4 * gq + r];

  float mrun[4], lrun[4];
  f32x4 oacc[4];
#pragma unroll
  for (int r = 0; r < 4; ++r) { mrun[r] = -1e30f; lrun[r] = 0.f; }
#pragma unroll
  for (int di = 0; di < 4; ++di) oacc[di] = fz;

  const u16* rbh = rbuf + (size_t)h * 2048 * 64;
  int bufi = 0;
  for (int t = chunk; t <= tmax; t += 2, bufi ^= 1) {
    if (t + 2 <= tmax) {
      STAGE(t + 2, bufi ^ 1);
      asm volatile("s_waitcnt vmcnt(4)" ::: "memory");
    } else {
      asm volatile("s_waitcnt vmcnt(0)" ::: "memory");
    }
    __builtin_amdgcn_sched_barrier(0);
    __builtin_amdgcn_s_barrier();
    __builtin_amdgcn_sched_barrier(0);

    const char* K = (const char*)ldsK[bufi];
    const char* V = (const char*)ldsV[bufi];
    float x[4][4];
#pragma unroll 1
    for (int jt = 0; jt < 4; ++jt) {
      int row = jt * 16 + cl;
      int base = row * 128, sw = (row & 7) << 4;
      bf16x8 k0 = *(const bf16x8*)(K + ((base + gq * 16) ^ sw));
      bf16x8 k1 = *(const bf16x8*)(K + ((base + 64 + gq * 16) ^ sw));
      f32x4 xq = mfma16x16x32(aU[0], k0, fz);
      xq = mfma16x16x32(aU[1], k1, xq);
      // relative bias: r rows (Rb+cl), direct from global (L2)
      int Rb = 64 * t + jt * 16 - i0 + 1008;
      int rr0 = min(Rb + cl, 2047), rr1 = min(Rb + 16 + cl, 2047);
      const u16* rp0 = rbh + (size_t)rr0 * 64 + gq * 8;
      const u16* rp1 = rbh + (size_t)rr1 * 64 + gq * 8;
      bf16x8 rf00 = *(const bf16x8*)(rp0);
      bf16x8 rf01 = *(const bf16x8*)(rp0 + 32);
      bf16x8 rf10 = *(const bf16x8*)(rp1);
      bf16x8 rf11 = *(const bf16x8*)(rp1 + 32);
      f32x4 b0 = mfma16x16x32(aV[0], rf00, fz);
      b0 = mfma16x16x32(aV[1], rf01, b0);
      f32x4 b1 = mfma16x16x32(aV[0], rf10, fz);
      b1 = mfma16x16x32(aV[1], rf11, b1);
      int ksv = kseg[(size_t)b * 2048 + 64 * t + jt * 16 + cl];
#pragma unroll
      for (int r = 0; r < 4; ++r) {
        int ri = 4 * gq + r;
        int lc = cl - ri + 15;  // in [0,30]
        int srcl = (gq << 4) | (lc & 15);
        float d0 = __shfl(b0[r], srcl);
        float d1 = __shfl(b1[r], srcl);
        float bdv = (lc < 16) ? d0 : d1;
        int j = 64 * t + jt * 16 + cl;
        bool ok = (j <= i0 + ri + 1024) && (ksv == qsv[r]);
        x[jt][r] = ok ? (xq[r] + bdv) * 0.125f : -1e30f;
      }
    }
    // online softmax over 64 keys (row spread over 16 lanes x 4 jt)
    char* Pm = (char*)ldsP[wv];
    float alf[4];
#pragma unroll
    for (int r = 0; r < 4; ++r) {
      float mx = fmaxf(fmaxf(x[0][r], x[1][r]), fmaxf(x[2][r], x[3][r]));
      mx = fmaxf(mx, __shfl_xor(mx, 1));
      mx = fmaxf(mx, __shfl_xor(mx, 2));
      mx = fmaxf(mx, __shfl_xor(mx, 4));
      mx = fmaxf(mx, __shfl_xor(mx, 8));
      float mold = mrun[r];
      float mnew = fmaxf(mold, mx);
      float al = __expf(mold - mnew);
      float p0 = __expf(x[0][r] - mnew);
      float p1 = __expf(x[1][r] - mnew);
      float p2 = __expf(x[2][r] - mnew);
      float p3 = __expf(x[3][r] - mnew);
      float s = p0 + p1 + p2 + p3;
      s += __shfl_xor(s, 1); s += __shfl_xor(s, 2);
      s += __shfl_xor(s, 4); s += __shfl_xor(s, 8);
      mrun[r] = mnew;
      lrun[r] = lrun[r] * al + s;
      alf[r] = al;
      int ri = 4 * gq + r;
      int bb = (ri & 7) << 4;
      *(u16*)(Pm + ((ri * 128 + cl * 2) ^ bb)) = f2bf(p0);
      *(u16*)(Pm + ((ri * 128 + (16 + cl) * 2) ^ bb)) = f2bf(p1);
      *(u16*)(Pm + ((ri * 128 + (32 + cl) * 2) ^ bb)) = f2bf(p2);
      *(u16*)(Pm + ((ri * 128 + (48 + cl) * 2) ^ bb)) = f2bf(p3);
    }
    f32x4 av = {alf[0], alf[1], alf[2], alf[3]};
#pragma unroll
    for (int di = 0; di < 4; ++di) oacc[di] *= av;
    // PV (wave-private P round trip; compiler orders lgkmcnt)
    int psw = (cl & 7) << 4;
    bf16x8 pf0 = *(const bf16x8*)(Pm + ((cl * 128 + gq * 16) ^ psw));
    bf16x8 pf1 = *(const bf16x8*)(Pm + ((cl * 128 + 64 + gq * 16) ^ psw));
#pragma unroll
    for (int di = 0; di < 4; ++di) {
      int row = di * 16 + cl;
      int base = row * 128, sw = (row & 7) << 4;
      bf16x8 v0 = *(const bf16x8*)(V + ((base + gq * 16) ^ sw));
      bf16x8 v1 = *(const bf16x8*)(V + ((base + 64 + gq * 16) ^ sw));
      oacc[di] = mfma16x16x32(pf0, v0, oacc[di]);
      oacc[di] = mfma16x16x32(pf1, v1, oacc[di]);
    }
    __builtin_amdgcn_sched_barrier(0);
    __builtin_amdgcn_s_barrier();  // protect cur buf before next-iter staging
    __builtin_amdgcn_sched_barrier(0);
  }
#undef STAGE

  // epilogue: raw partials (no 1/l) + (m,l)
#pragma unroll
  for (int r = 0; r < 4; ++r) {
    int iq = i0 + 4 * gq + r;
    size_t rowp = ((size_t)bh * 2 + chunk) * 1024 + iq;
#pragma unroll
    for (int di = 0; di < 4; ++di)
      pO[rowp * 64 + di * 16 + cl] = f2bf(oacc[di][r]);
    if (cl == 0) {
      pml[rowp * 2] = mrun[r];
      pml[rowp * 2 + 1] = lrun[r];
    }
  }
}

// --- split-key combine -------------------------------------------------------
__global__ __launch_bounds__(256) void combine_kernel(
    const u16* __restrict__ pO, const float* __restrict__ pml,
    u16* __restrict__ obf) {
  int gid = blockIdx.x * 256 + threadIdx.x;  // 262144
  int d8 = (gid & 7) * 8;
  int row = gid >> 3;  // bh*1024 + iq
  int bh = row >> 10, iq = row & 1023;
  int b = bh >> 4, h = bh & 15;
  size_t r0 = ((size_t)bh * 2) * 1024 + iq;
  size_t r1 = r0 + 1024;
  float m0 = pml[r0 * 2], l0 = pml[r0 * 2 + 1];
  float m1 = pml[r1 * 2], l1 = pml[r1 * 2 + 1];
  float ms = fmaxf(m0, m1);
  float w0 = __expf(m0 - ms), w1 = __expf(m1 - ms);
  float inv = 1.0f / fmaxf(l0 * w0 + l1 * w1, 1e-30f);
  bf16x8 a = *(const bf16x8*)(pO + r0 * 64 + d8);
  bf16x8 c = *(const bf16x8*)(pO + r1 * 64 + d8);
  bf16x8 o;
#pragma unroll
  for (int j = 0; j < 8; ++j) {
    float f = (bf2f((u16)a[j]) * w0 + bf2f((u16)c[j]) * w1) * inv;
    o[j] = (short)f2bf(f);
  }
  *(bf16x8*)(obf + ((size_t)b * 1024 + iq) * 1024 + h * 64 + d8) = o;
}

// ---------------------------------------------------------------------------
extern "C" void kernel_launch(void* const* d_in, const int* in_sizes, int n_in,
                              void* d_out, int out_size, void* d_ws, size_t ws_size,
                              hipStream_t stream) {
  (void)in_sizes; (void)n_in; (void)out_size; (void)ws_size;
  const float* x           = (const float*)d_in[0];
  const int*   mask        = (const int*)d_in[1];
  const int*   mem_mask    = (const int*)d_in[3];
  const float* cache_key   = (const float*)d_in[4];
  const float* cache_value = (const float*)d_in[5];
  const int*   cache_mask  = (const int*)d_in[6];
  const float* rel_emb     = (const float*)d_in[7];
  const float* Wq          = (const float*)d_in[8];
  const float* Wk          = (const float*)d_in[9];
  const float* Wv          = (const float*)d_in[10];
  const float* Wr          = (const float*)d_in[11];
  const float* uvec        = (const float*)d_in[12];
  const float* vvec        = (const float*)d_in[13];
  const float* Wo          = (const float*)d_in[14];
  float* dout = (float*)d_out;

  char* W = (char*)d_ws;  // ~50.6 MB of workspace used
  u16* xbf   = (u16*)(W + (0u << 20));   // dead after projection GEMMs
  u16* relbf = (u16*)(W + (4u << 20));   // dead after projection GEMMs
  u16* pO    = (u16*)(W + (0u << 20));   // reuses xbf+relbf (8 MiB exactly)
  u16* wt5   = (u16*)(W + (8u << 20));
  u16* kbuf  = (u16*)(W + (18u << 20));
  u16* vtbuf = (u16*)(W + (26u << 20));
  u16* rbuf  = (u16*)(W + (34u << 20));
  u16* qu    = (u16*)(W + (38u << 20));
  u16* qv    = (u16*)(W + (42u << 20));
  u16* obf   = (u16*)(W + (46u << 20));
  int* qseg  = (int*)(W + (50u << 20));
  int* kseg  = (int*)(W + (50u << 20) + 8192);
  float* pml = (float*)(W + (50u << 20) + 32768);

  seg_scan_kernel<<<dim3(2), dim3(64), 0, stream>>>(mask, mem_mask, cache_mask, qseg, kseg);
  cvt_bf16_kernel<<<dim3(2048), dim3(256), 0, stream>>>(x, xbf, 2097152);
  cvt_bf16_kernel<<<dim3(2048), dim3(256), 0, stream>>>(rel_emb, relbf, 2097152);
  tr_w_kernel<<<dim3(32, 32), dim3(256), 0, stream>>>(Wq, wt5);
  tr_w_kernel<<<dim3(32, 32), dim3(256), 0, stream>>>(Wk, wt5 + (1u << 20));
  tr_w_kernel<<<dim3(32, 32), dim3(256), 0, stream>>>(Wv, wt5 + (2u << 20));
  tr_w_kernel<<<dim3(32, 32), dim3(256), 0, stream>>>(Wr, wt5 + (3u << 20));
  tr_w_kernel<<<dim3(32, 32), dim3(256), 0, stream>>>(Wo, wt5 + (4u << 20));
  ck_perm_kernel<<<dim3(2048), dim3(256), 0, stream>>>(cache_key, kbuf);
  cv_tr_kernel<<<dim3(32, 2, 32), dim3(256), 0, stream>>>(cache_value, vtbuf);
  gemm_proj_kernel<<<dim3(16, 32, 4), dim3(256), 0, stream>>>(
      xbf, relbf, obf, wt5, qu, qv, kbuf, vtbuf, rbuf, dout, uvec, vvec, -1);
  attn_kernel<<<dim3(32, 16, 2), dim3(256), 0, stream>>>(qu, qv, kbuf, vtbuf, rbuf,
                                                         qseg, kseg, pO, pml);
  combine_kernel<<<dim3(1024), dim3(256), 0, stream>>>(pO, pml, obf);
  gemm_proj_kernel<<<dim3(16, 32, 1), dim3(256), 0, stream>>>(
      xbf, relbf, obf, wt5, qu, qv, kbuf, vtbuf, rbuf, dout, uvec, vvec, 4);
}